// Round 11
// baseline (112.142 us; speedup 1.0000x reference)
//
#include <hip/hip_runtime.h>

// Quantized 3x3 conv, stride 1, pad 1 (MI355X / gfx950):
//   x: [32,64,112,112] fp32 -> uint4-range [0,15]
//   w: [128,64,3,3]    fp32 -> int4-range  [-8,7]
//   out: [32,128,112,112] fp32 (integer-exact)
//
// R11 = R9's kernel with the 4-row structure redone via
// __builtin_amdgcn_global_load_lds (zero-VGPR staging; R10's register
// staging blew the VGPR budget -> 1 block/CU -> regression).
//   stage rows 0..3 (DMA) -> barrier -> issue rows 4..5 (DMA, in flight
//   across pair-0 compute) -> pair-0 K-loop -> barrier (drains DMA only,
//   no stores pending) -> pair-0 stores -> pair-1 K-loop -> pair-1 stores.
//
// k_prep: blocks 0..287: quantize weights -> fragment-major
//           wq[ks][coTile(8)][lane(64)][16B]  (exact MFMA B-fragment order)
//         blocks 288+ : quantize+transpose x -> xq[n][hp][wp][c] int8
//           (padded 114x114, zero border).
// k_conv: block = 4 output rows x 128 cout, 512 thr / 8 waves.
//         Wave = 1 row (7x16 sp) x 32 co per pair; weights from global L2,
//         prefetch depth 2; 14 MFMA v_mfma_i32_16x16x64_i8 per ks per wave.

#define CIN  64
#define HH   112
#define WW   112
#define HW   (HH * WW)
#define COUT 128
#define HP   114
#define WP   114
#define KTOT 576

#define XQ_BYTES (32 * HP * WP * 64)     // 26,615,808
#define NWBLK 288                        // 288*256 = 73728 weight bytes
#define NXBLK (32 * 57)                  // activation prep blocks (2 rows each)
#define NCONV 896                        // 32 img * 28 quad-row strips = 8*112

#define ROWB (WP * 64)                   // 7296 B per padded row
#define SLAB_BYTES (6 * ROWB)            // 43,776 B (6 padded rows)
#define INIT_B (4 * ROWB)                // 29,184 B: rows 0..3
#define MID_B  (2 * ROWB)                // 14,592 B: rows 4..5

typedef __attribute__((ext_vector_type(4))) int int32x4;

__device__ __forceinline__ void gld_lds16(const char* g, char* l) {
    __builtin_amdgcn_global_load_lds(
        (const __attribute__((address_space(1))) void*)g,
        (__attribute__((address_space(3))) void*)l, 16, 0, 0);
}

__global__ __launch_bounds__(256) void k_prep(const float* __restrict__ x,
                                              const float* __restrict__ w,
                                              char* __restrict__ xq,
                                              char* __restrict__ wq) {
    const int bid = blockIdx.x, tid = threadIdx.x;
    if (bid < NWBLK) {
        // ---- weights, fragment-major: idx = dest byte ----
        // idx = ks*8192 + ct*1024 + ln*16 + j
        // -> cout = ct*16 + (ln&15), c = (ln>>4)*16 + j, kh = ks/3, kw = ks%3
        int idx = bid * 256 + tid;
        int ks  = idx / 8192;
        int r2  = idx % 8192;
        int ct  = r2 / 1024;
        int r3  = r2 % 1024;
        int ln  = r3 / 16;
        int j   = r3 % 16;
        int o   = ct * 16 + (ln & 15);
        int c   = (ln >> 4) * 16 + j;
        int kh  = ks / 3, kw = ks % 3;
        float q = fminf(fmaxf(rintf(w[((o * CIN + c) * 3 + kh) * 3 + kw]), -8.0f), 7.0f);
        wq[idx] = (char)(int)q;
        return;
    }
    // ---- activations: xq[n][hp][wp][c], zero border ----
    const int rid = bid - NWBLK;          // 0..1823
    const int n  = rid / 57;
    const int hp = (rid % 57) * 2 + (tid >> 7);
    const int wp = tid & 127;
    if (wp >= WP) return;
    char* dst = xq + (((size_t)n * HP + hp) * WP + wp) * 64;
    int32x4* d4 = (int32x4*)dst;
    if (hp == 0 || hp == HP - 1 || wp == 0 || wp == WP - 1) {
#pragma unroll
        for (int i = 0; i < 4; ++i) d4[i] = (int32x4)(0);
        return;
    }
    const int h = hp - 1, ww = wp - 1;
    const float* px = x + (((size_t)n * CIN) * HH + h) * WW + ww;
    unsigned int buf[16];
#pragma unroll
    for (int cw = 0; cw < 16; ++cw) {
        unsigned int word = 0;
#pragma unroll
        for (int j = 0; j < 4; ++j) {
            float v = px[(size_t)(cw * 4 + j) * HW];
            float q = fminf(fmaxf(rintf(v), 0.0f), 15.0f);
            word |= ((unsigned int)(int)q) << (8 * j);
        }
        buf[cw] = word;
    }
#pragma unroll
    for (int i = 0; i < 4; ++i) {
        int32x4 v;
        v.x = (int)buf[i * 4 + 0];
        v.y = (int)buf[i * 4 + 1];
        v.z = (int)buf[i * 4 + 2];
        v.w = (int)buf[i * 4 + 3];
        d4[i] = v;
    }
}

__global__ __launch_bounds__(512, 4) void k_conv(const char* __restrict__ xq,
                                                 const char* __restrict__ wq,
                                                 float* __restrict__ out) {
    __shared__ char slab[SLAB_BYTES];     // 43,776 B: padded rows h0..h0+5

    const int tid = threadIdx.x;
    // XCD chunking (896 = 8*112, bijective): consecutive nids = consecutive
    // 4-row strips of the same image -> halo L2 reuse within an XCD.
    const int nid = (blockIdx.x & 7) * (NCONV / 8) + (blockIdx.x >> 3);
    const int n   = nid / 28;
    const int h0  = (nid % 28) * 4;       // output rows h0..h0+3

    const int wave = tid >> 6;            // 0..7
    const int lane = tid & 63;

    // padded rows h0..h0+5 of xq are CONTIGUOUS in memory
    const char* src = xq + (size_t)n * (HP * ROWB) + (size_t)h0 * ROWB;

    // ---- stage rows 0..3 via global_load_lds (wave-uniform LDS base) ----
#pragma unroll
    for (int k = 0; k < 4; ++k) {
        const int ch  = wave + k * 8;          // 0..31 (need 0..28.5)
        const int off = ch * 1024 + lane * 16;
        if (off < INIT_B)
            gld_lds16(src + off, slab + ch * 1024);
    }
    __syncthreads();

    // ---- issue rows 4..5 DMA now; in flight across pair-0 compute ----
#pragma unroll
    for (int k = 0; k < 2; ++k) {
        const int ch  = wave + k * 8;          // 0..15 (need 0..14.25)
        const int off = ch * 1024 + lane * 16;
        if (off < MID_B)
            gld_lds16(src + INIT_B + off, slab + INIT_B + ch * 1024);
    }

    const int l15 = lane & 15;
    const int lk  = lane >> 4;            // 16-byte k-chunk within 64 channels
    const int rw  = wave >> 2;            // output row within pair (0..1)
    const int Q   = wave & 3;             // cout quarter (32 couts)

    // B (weights, fragment-major): frag(ks, ct=Q*2+tO) at (ks*8+ct)*1024 + lane*16
    const char* wbase = wq + (Q * 2) * 1024 + lane * 16;

    int32x4 accA[7][2], accB[7][2];

    // ================= pair 0: output rows h0+rw, slab rows 0..3 =================
    {
#pragma unroll
        for (int i = 0; i < 7; ++i) { accA[i][0] = (int32x4)(0); accA[i][1] = (int32x4)(0); }
        int32x4 b0[2], b1[2], b2[2];
        b0[0] = *(const int32x4*)(wbase);
        b0[1] = *(const int32x4*)(wbase + 1024);
        b1[0] = *(const int32x4*)(wbase + 8192);
        b1[1] = *(const int32x4*)(wbase + 8192 + 1024);
#pragma unroll
        for (int ks = 0; ks < 9; ++ks) {
            const int ksn = (ks + 2 <= 8) ? ks + 2 : 8;
            b2[0] = *(const int32x4*)(wbase + ksn * 8192);
            b2[1] = *(const int32x4*)(wbase + ksn * 8192 + 1024);
            const int kh = ks / 3, kw = ks % 3;
            const char* arow = &slab[(((rw + kh) * WP) + l15 + kw) * 64 + lk * 16];
            int32x4 af[7];
#pragma unroll
            for (int wt = 0; wt < 7; ++wt)
                af[wt] = *(const int32x4*)(arow + wt * 1024);
#pragma unroll
            for (int tO = 0; tO < 2; ++tO)
#pragma unroll
                for (int wt = 0; wt < 7; ++wt)
                    accA[wt][tO] = __builtin_amdgcn_mfma_i32_16x16x64_i8(af[wt], b0[tO], accA[wt][tO], 0, 0, 0);
            b0[0] = b1[0]; b0[1] = b1[1];
            b1[0] = b2[0]; b1[1] = b2[1];
        }
    }

    // Barrier: waits for rows 4..5 DMA (already landed under pair-0 compute).
    // No stores issued yet, so nothing drains through the store queue here.
    __syncthreads();

    // ---- pair-0 epilogue: D col(l15)=cout, row(lk*4+reg)=spatial w ----
    {
        const int hgl = h0 + rw;
#pragma unroll
        for (int wt = 0; wt < 7; ++wt)
#pragma unroll
            for (int tO = 0; tO < 2; ++tO) {
                const int co = Q * 32 + tO * 16 + l15;
                float4 v;
                v.x = (float)accA[wt][tO][0];
                v.y = (float)accA[wt][tO][1];
                v.z = (float)accA[wt][tO][2];
                v.w = (float)accA[wt][tO][3];
                *(float4*)(&out[(((size_t)n * COUT + co) * HH + hgl) * WW + wt * 16 + lk * 4]) = v;
            }
    }

    // ================= pair 1: output rows h0+2+rw, slab rows 2..5 =================
    {
#pragma unroll
        for (int i = 0; i < 7; ++i) { accB[i][0] = (int32x4)(0); accB[i][1] = (int32x4)(0); }
        int32x4 b0[2], b1[2], b2[2];
        b0[0] = *(const int32x4*)(wbase);
        b0[1] = *(const int32x4*)(wbase + 1024);
        b1[0] = *(const int32x4*)(wbase + 8192);
        b1[1] = *(const int32x4*)(wbase + 8192 + 1024);
#pragma unroll
        for (int ks = 0; ks < 9; ++ks) {
            const int ksn = (ks + 2 <= 8) ? ks + 2 : 8;
            b2[0] = *(const int32x4*)(wbase + ksn * 8192);
            b2[1] = *(const int32x4*)(wbase + ksn * 8192 + 1024);
            const int kh = ks / 3, kw = ks % 3;
            const char* arow = &slab[(((2 + rw + kh) * WP) + l15 + kw) * 64 + lk * 16];
            int32x4 af[7];
#pragma unroll
            for (int wt = 0; wt < 7; ++wt)
                af[wt] = *(const int32x4*)(arow + wt * 1024);
#pragma unroll
            for (int tO = 0; tO < 2; ++tO)
#pragma unroll
                for (int wt = 0; wt < 7; ++wt)
                    accB[wt][tO] = __builtin_amdgcn_mfma_i32_16x16x64_i8(af[wt], b0[tO], accB[wt][tO], 0, 0, 0);
            b0[0] = b1[0]; b0[1] = b1[1];
            b1[0] = b2[0]; b1[1] = b2[1];
        }
        const int hgl = h0 + 2 + rw;
#pragma unroll
        for (int wt = 0; wt < 7; ++wt)
#pragma unroll
            for (int tO = 0; tO < 2; ++tO) {
                const int co = Q * 32 + tO * 16 + l15;
                float4 v;
                v.x = (float)accB[wt][tO][0];
                v.y = (float)accB[wt][tO][1];
                v.z = (float)accB[wt][tO][2];
                v.w = (float)accB[wt][tO][3];
                *(float4*)(&out[(((size_t)n * COUT + co) * HH + hgl) * WW + wt * 16 + lk * 4]) = v;
            }
    }
}

extern "C" void kernel_launch(void* const* d_in, const int* in_sizes, int n_in,
                              void* d_out, int out_size, void* d_ws, size_t ws_size,
                              hipStream_t stream) {
    const float* x = (const float*)d_in[0];
    const float* w = (const float*)d_in[1];
    float* out = (float*)d_out;

    char* xq = (char*)d_ws;
    char* wq = xq + XQ_BYTES;

    hipLaunchKernelGGL(k_prep, dim3(NWBLK + NXBLK), dim3(256), 0, stream, x, w, xq, wq);
    hipLaunchKernelGGL(k_conv, dim3(NCONV), dim3(512), 0, stream, xq, wq, out);
}

// Round 13
// 92.909 us; speedup vs baseline: 1.2070x; 1.2070x over previous
//
#include <hip/hip_runtime.h>

// Quantized 3x3 conv, stride 1, pad 1 (MI355X / gfx950):
//   x: [32,64,112,112] fp32 -> uint4-range [0,15]
//   w: [128,64,3,3]    fp32 -> int4-range  [-8,7]
//   out: [32,128,112,112] fp32 (integer-exact)
//
// R13 = R9 (best, 87.2 us) + ONE change: NONTEMPORAL epilogue stores
// (via ext_vector_type float4 -- HIP_vector_type float4 is rejected by
// __builtin_nontemporal_store). The 205 MB out stream is write-once -> nt
// keeps it from evicting the L3-resident xq (26.6 MB, re-read ~2x gross)
// and the L2-resident weights.
//
// k_prep: blocks 0..287: quantize weights -> fragment-major
//           wq[ks][coTile(8)][lane(64)][16B]  (exact MFMA B-fragment order)
//         blocks 288+ : quantize+transpose x -> xq[n][hp][wp][c] int8
//           (padded 114x114, zero border).
// k_conv: block = 2 output rows x 128 cout, 512 thr / 8 waves.
//         Stage padded rows h0..h0+3 (29,184 contiguous bytes of xq) into
//         LDS with a linear coalesced copy. Wave = 1 row (7x16 sp) x 32 co.
//         Weights from global L2, prefetch depth 2. 14 MFMA
//         v_mfma_i32_16x16x64_i8 per ks per wave.

#define CIN  64
#define HH   112
#define WW   112
#define HW   (HH * WW)
#define COUT 128
#define HP   114
#define WP   114
#define KTOT 576

#define XQ_BYTES (32 * HP * WP * 64)     // 26,615,808
#define NWBLK 288                        // 288*256 = 73728 weight bytes
#define NXBLK (32 * 57)                  // activation prep blocks (2 rows each)
#define NCONV 1792                       // 32 img * 56 row-pairs = 8 * 224

#define SLAB_BYTES (4 * WP * 64)         // 29,184 B (4 padded rows)
#define SLAB_U16   (SLAB_BYTES / 16)     // 1824 16-byte units

typedef __attribute__((ext_vector_type(4))) int   int32x4;
typedef __attribute__((ext_vector_type(4))) float f32x4;

__global__ __launch_bounds__(256) void k_prep(const float* __restrict__ x,
                                              const float* __restrict__ w,
                                              char* __restrict__ xq,
                                              char* __restrict__ wq) {
    const int bid = blockIdx.x, tid = threadIdx.x;
    if (bid < NWBLK) {
        // ---- weights, fragment-major: idx = dest byte ----
        // idx = ks*8192 + ct*1024 + ln*16 + j
        // -> cout = ct*16 + (ln&15), c = (ln>>4)*16 + j, kh = ks/3, kw = ks%3
        int idx = bid * 256 + tid;
        int ks  = idx / 8192;
        int r2  = idx % 8192;
        int ct  = r2 / 1024;
        int r3  = r2 % 1024;
        int ln  = r3 / 16;
        int j   = r3 % 16;
        int o   = ct * 16 + (ln & 15);
        int c   = (ln >> 4) * 16 + j;
        int kh  = ks / 3, kw = ks % 3;
        float q = fminf(fmaxf(rintf(w[((o * CIN + c) * 3 + kh) * 3 + kw]), -8.0f), 7.0f);
        wq[idx] = (char)(int)q;
        return;
    }
    // ---- activations: xq[n][hp][wp][c], zero border ----
    const int rid = bid - NWBLK;          // 0..1823
    const int n  = rid / 57;
    const int hp = (rid % 57) * 2 + (tid >> 7);
    const int wp = tid & 127;
    if (wp >= WP) return;
    char* dst = xq + (((size_t)n * HP + hp) * WP + wp) * 64;
    int32x4* d4 = (int32x4*)dst;
    if (hp == 0 || hp == HP - 1 || wp == 0 || wp == WP - 1) {
#pragma unroll
        for (int i = 0; i < 4; ++i) d4[i] = (int32x4)(0);
        return;
    }
    const int h = hp - 1, ww = wp - 1;
    const float* px = x + (((size_t)n * CIN) * HH + h) * WW + ww;
    unsigned int buf[16];
#pragma unroll
    for (int cw = 0; cw < 16; ++cw) {
        unsigned int word = 0;
#pragma unroll
        for (int j = 0; j < 4; ++j) {
            float v = px[(size_t)(cw * 4 + j) * HW];
            float q = fminf(fmaxf(rintf(v), 0.0f), 15.0f);
            word |= ((unsigned int)(int)q) << (8 * j);
        }
        buf[cw] = word;
    }
#pragma unroll
    for (int i = 0; i < 4; ++i) {
        int32x4 v;
        v.x = (int)buf[i * 4 + 0];
        v.y = (int)buf[i * 4 + 1];
        v.z = (int)buf[i * 4 + 2];
        v.w = (int)buf[i * 4 + 3];
        d4[i] = v;
    }
}

__global__ __launch_bounds__(512, 4) void k_conv(const char* __restrict__ xq,
                                                 const char* __restrict__ wq,
                                                 float* __restrict__ out) {
    __shared__ char slab[SLAB_BYTES];     // 29,184 B: padded rows h0..h0+3

    const int tid = threadIdx.x;
    // XCD chunking (1792 = 8*224, bijective): consecutive nids = consecutive
    // row-pairs of the same image -> halo-row L2 reuse within an XCD.
    const int nid = (blockIdx.x & 7) * (NCONV / 8) + (blockIdx.x >> 3);
    const int n   = nid / 56;
    const int h0  = (nid % 56) * 2;

    // ---- stage: rows h0..h0+3 of xq are CONTIGUOUS -> linear memcpy ----
    const char* src = xq + (size_t)n * (HP * WP * 64) + (size_t)h0 * (WP * 64);
#pragma unroll
    for (int k = 0; k < 4; ++k) {
        const int u = tid + k * 512;
        if (u < SLAB_U16)
            *(int32x4*)(&slab[u * 16]) = *(const int32x4*)(src + u * 16);
    }
    __syncthreads();

    const int wave = tid >> 6;            // 0..7
    const int lane = tid & 63;
    const int l15  = lane & 15;
    const int lk   = lane >> 4;           // 16-byte k-chunk within 64 channels
    const int rw   = wave >> 2;           // output row within pair (0..1)
    const int Q    = wave & 3;            // cout quarter (32 couts)

    // B (weights, fragment-major): frag(ks, ct=Q*2+tO) at (ks*8+ct)*1024 + lane*16
    const char* wbase = wq + (Q * 2) * 1024 + lane * 16;

    int32x4 acc[7][2];
#pragma unroll
    for (int i = 0; i < 7; ++i) {
        acc[i][0] = (int32x4)(0);
        acc[i][1] = (int32x4)(0);
    }

    // Weight prefetch depth 2: b0 = frag(ks), b1 = frag(ks+1), issue ks+2.
    int32x4 b0[2], b1[2], b2[2];
    b0[0] = *(const int32x4*)(wbase);
    b0[1] = *(const int32x4*)(wbase + 1024);
    b1[0] = *(const int32x4*)(wbase + 8192);
    b1[1] = *(const int32x4*)(wbase + 8192 + 1024);

#pragma unroll
    for (int ks = 0; ks < 9; ++ks) {
        {
            const int ksn = (ks + 2 <= 8) ? ks + 2 : 8;   // clamp: stay in-bounds
            b2[0] = *(const int32x4*)(wbase + ksn * 8192);
            b2[1] = *(const int32x4*)(wbase + ksn * 8192 + 1024);
        }
        const int kh = ks / 3, kw = ks % 3;
        // A: slab row (rw+kh), padded col (wt*16 + l15 + kw), chunk lk
        const char* arow = &slab[(((rw + kh) * WP) + l15 + kw) * 64 + lk * 16];
        int32x4 af[7];
#pragma unroll
        for (int wt = 0; wt < 7; ++wt)
            af[wt] = *(const int32x4*)(arow + wt * 1024);   // wt*16 cols * 64B
#pragma unroll
        for (int tO = 0; tO < 2; ++tO)
#pragma unroll
            for (int wt = 0; wt < 7; ++wt)
                acc[wt][tO] = __builtin_amdgcn_mfma_i32_16x16x64_i8(af[wt], b0[tO], acc[wt][tO], 0, 0, 0);
        b0[0] = b1[0]; b0[1] = b1[1];
        b1[0] = b2[0]; b1[1] = b2[1];
    }

    // ---- epilogue: D col(l15)=cout, row(lk*4+reg)=spatial w -> NT float4 ----
    const int hgl = h0 + rw;
#pragma unroll
    for (int wt = 0; wt < 7; ++wt) {
#pragma unroll
        for (int tO = 0; tO < 2; ++tO) {
            const int co = Q * 32 + tO * 16 + l15;
            f32x4 v;
            v.x = (float)acc[wt][tO][0];
            v.y = (float)acc[wt][tO][1];
            v.z = (float)acc[wt][tO][2];
            v.w = (float)acc[wt][tO][3];
            __builtin_nontemporal_store(
                v, (f32x4*)(&out[(((size_t)n * COUT + co) * HH + hgl) * WW + wt * 16 + lk * 4]));
        }
    }
}

extern "C" void kernel_launch(void* const* d_in, const int* in_sizes, int n_in,
                              void* d_out, int out_size, void* d_ws, size_t ws_size,
                              hipStream_t stream) {
    const float* x = (const float*)d_in[0];
    const float* w = (const float*)d_in[1];
    float* out = (float*)d_out;

    char* xq = (char*)d_ws;
    char* wq = xq + XQ_BYTES;

    hipLaunchKernelGGL(k_prep, dim3(NWBLK + NXBLK), dim3(256), 0, stream, x, w, xq, wq);
    hipLaunchKernelGGL(k_conv, dim3(NCONV), dim3(512), 0, stream, xq, wq, out);
}